// Round 19
// baseline (4899.534 us; speedup 1.0000x reference)
//
#include <hip/hip_runtime.h>
#include <math.h>

#define N_NODES 100000
#define N_EDGES 1600000
#define HDIM 128
#define NBLK 16
#define NREL 200
#define NW_AGG 8192   // balanced waves (fallback path)
#define TILE_E 64     // edges per block in msg GEMM
#define NT 8          // node-tile for node kernels
#define NG 10         // node groups (msg path)
#define GSZ 10000     // nodes per group
#define NBUCK (NG * NREL)
#define MAXE_G 176000 // max edges per group (mean 160K, fixed dataset)

typedef unsigned short ushort_t;
typedef unsigned int uint_t;
typedef _Float16 h2 __attribute__((ext_vector_type(2)));

__device__ __forceinline__ ushort_t f2h(float f) {
  _Float16 h = (_Float16)f;
  return __builtin_bit_cast(unsigned short, h);
}
__device__ __forceinline__ float h2f(ushort_t b) {
  return (float)__builtin_bit_cast(_Float16, b);
}

#if defined(__has_builtin) && __has_builtin(__builtin_amdgcn_fdot2)
#define FDOT2(accv, au, bu)                                                    \
  accv = __builtin_amdgcn_fdot2(__builtin_bit_cast(h2, au),                    \
                                __builtin_bit_cast(h2, bu), accv, false);
#else
#define FDOT2(accv, au, bu)                                                    \
  {                                                                            \
    h2 av_ = __builtin_bit_cast(h2, au);                                       \
    h2 bv_ = __builtin_bit_cast(h2, bu);                                       \
    accv = fmaf((float)av_[0], (float)bv_[0], accv);                           \
    accv = fmaf((float)av_[1], (float)bv_[1], accv);                           \
  }
#endif

#if defined(__has_builtin) && __has_builtin(__builtin_amdgcn_global_load_lds)
#define HAVE_GLL 1
#else
#define HAVE_GLL 0
#endif

// Stage 32 h-rows (8KB) into wave slab (fallback agg path).
#if HAVE_GLL
#define STAGE_H32(HSRC, SMEMW)                                                 \
  {                                                                            \
    _Pragma("unroll") for (int i_ = 0; i_ < 8; ++i_) {                         \
      int ei_ = (i_ << 2) + (l >> 4);                                          \
      if (ei_ >= m) ei_ = m - 1;                                               \
      int ss_ = __shfl(r.x, ei_);                                              \
      const ushort_t* gsrc_ = HSRC + ((long)ss_ << 7) + ((l & 15) << 3);       \
      __builtin_amdgcn_global_load_lds(                                        \
          (const __attribute__((address_space(1))) unsigned int*)gsrc_,        \
          (__attribute__((address_space(3))) unsigned int*)&SMEMW[i_ << 9],    \
          16, 0, 0);                                                           \
    }                                                                          \
    asm volatile("s_waitcnt vmcnt(0)" ::: "memory");                           \
  }
#else
#define STAGE_H32(HSRC, SMEMW)                                                 \
  {                                                                            \
    _Pragma("unroll") for (int i_ = 0; i_ < 8; ++i_) {                         \
      int ei_ = (i_ << 2) + (l >> 4);                                          \
      if (ei_ >= m) ei_ = m - 1;                                               \
      int ss_ = __shfl(r.x, ei_);                                              \
      const ushort_t* gsrc_ = HSRC + ((long)ss_ << 7) + ((l & 15) << 3);       \
      uint4 t_ = *(const uint4*)gsrc_;                                         \
      *(uint4*)&SMEMW[(i_ << 9) + (l << 3)] = t_;                              \
    }                                                                          \
  }
#endif

// Stage up to 16 h-rows (4KB) into wave slab (msg GEMM path).
#if HAVE_GLL
#define STAGE16R(HSRC, SLABP, RR, MM, LL)                                      \
  {                                                                            \
    _Pragma("unroll") for (int i_ = 0; i_ < 4; ++i_) {                         \
      int ei_ = (i_ << 2) + (LL >> 4);                                         \
      if (ei_ >= MM) ei_ = MM - 1;                                             \
      int ss_ = __shfl(RR.x, ei_);                                             \
      const ushort_t* gsrc_ = HSRC + ((long)ss_ << 7) + ((LL & 15) << 3);      \
      __builtin_amdgcn_global_load_lds(                                        \
          (const __attribute__((address_space(1))) unsigned int*)gsrc_,        \
          (__attribute__((address_space(3))) unsigned int*)&SLABP[i_ << 9],    \
          16, 0, 0);                                                           \
    }                                                                          \
    asm volatile("s_waitcnt vmcnt(0)" ::: "memory");                           \
  }
#else
#define STAGE16R(HSRC, SLABP, RR, MM, LL)                                      \
  {                                                                            \
    _Pragma("unroll") for (int i_ = 0; i_ < 4; ++i_) {                         \
      int ei_ = (i_ << 2) + (LL >> 4);                                         \
      if (ei_ >= MM) ei_ = MM - 1;                                             \
      int ss_ = __shfl(RR.x, ei_);                                             \
      const ushort_t* gsrc_ = HSRC + ((long)ss_ << 7) + ((LL & 15) << 3);      \
      uint4 t_ = *(const uint4*)gsrc_;                                         \
      *(uint4*)&SLABP[(i_ << 9) + (LL << 3)] = t_;                             \
    }                                                                          \
  }
#endif

// ================= build kernels =================
__global__ __launch_bounds__(256) void hist_deg(const int* __restrict__ dst,
                                                int* __restrict__ deg) {
  int e = blockIdx.x * 256 + threadIdx.x;
  if (e < N_EDGES) atomicAdd(&deg[dst[e]], 1);
}

__global__ __launch_bounds__(256) void hist_grel(const int* __restrict__ dst,
                                                 const int* __restrict__ etype,
                                                 int* __restrict__ cntB) {
  int e = blockIdx.x * 256 + threadIdx.x;
  if (e >= N_EDGES) return;
  int b = (dst[e] / GSZ) * NREL + etype[e];
  atomicAdd(&cntB[b], 1);
}

// generalized single-block exclusive scan over n elems; writes out[n]=total
__global__ __launch_bounds__(1024) void scanN(const int* __restrict__ in,
                                              int* __restrict__ out, int n) {
  __shared__ int wsum[16];
  __shared__ int carry_s;
  int tid = threadIdx.x, lane = tid & 63, wid = tid >> 6;
  if (tid == 0) carry_s = 0;
  __syncthreads();
  for (int base = 0; base < n; base += 1024) {
    int i = base + tid;
    int v = (i < n) ? in[i] : 0;
    int x = v;
#pragma unroll
    for (int s = 1; s < 64; s <<= 1) {
      int t = __shfl_up(x, s);
      if (lane >= s) x += t;
    }
    if (lane == 63) wsum[wid] = x;
    __syncthreads();
    if (wid == 0) {
      int y = (lane < 16) ? wsum[lane] : 0;
#pragma unroll
      for (int s = 1; s < 16; s <<= 1) {
        int t = __shfl_up(y, s);
        if (lane >= s) y += t;
      }
      if (lane < 16) wsum[lane] = y;
    }
    __syncthreads();
    int carry = carry_s;
    int wbase = (wid > 0) ? wsum[wid - 1] : 0;
    if (i < n) out[i] = carry + wbase + (x - v);
    __syncthreads();
    if (tid == 0) carry_s = carry + wsum[15];
    __syncthreads();
  }
  if (threadIdx.x == 0) out[n] = carry_s;
}

__global__ __launch_bounds__(256) void calc_tc(const int* __restrict__ cntB,
                                               int* __restrict__ tcB) {
  int i = blockIdx.x * 256 + threadIdx.x;
  if (i < NBUCK) tcB[i] = (cntB[i] + TILE_E - 1) / TILE_E;
}

// fallback: dst-CSR records {src, etype, norm}
__global__ __launch_bounds__(256) void scatter_rec(
    const int* __restrict__ src, const int* __restrict__ dst,
    const int* __restrict__ etype, const float* __restrict__ norm,
    const int* __restrict__ offsets, int* __restrict__ cursor,
    int4* __restrict__ rec) {
  int e = blockIdx.x * 256 + threadIdx.x;
  if (e >= N_EDGES) return;
  int d = dst[e];
  int pos = offsets[d] + atomicAdd(&cursor[d], 1);
  rec[pos] = make_int4(src[e], etype[e], __float_as_int(norm[e]), 0);
}

// msg path: group-major relation-sorted records {src, group-local csr pos, norm}
__global__ __launch_bounds__(256) void scatter2g(
    const int* __restrict__ src, const int* __restrict__ dst,
    const int* __restrict__ etype, const float* __restrict__ norm,
    const int* __restrict__ offsets, int* __restrict__ cursor,
    const int* __restrict__ offB, int* __restrict__ curB,
    int4* __restrict__ rec2) {
  int e = blockIdx.x * 256 + threadIdx.x;
  if (e >= N_EDGES) return;
  int d = dst[e];
  int pc = offsets[d] + atomicAdd(&cursor[d], 1);
  int g = d / GSZ;
  int b = g * NREL + etype[e];
  int pr = offB[b] + atomicAdd(&curB[b], 1);
  int pcl = pc - offsets[g * GSZ];  // group-local csr position
  rec2[pr] = make_int4(src[e], pcl, __float_as_int(norm[e]), 0);
}

__global__ __launch_bounds__(256) void calc_ranges(const int* __restrict__ offsets,
                                                   int* __restrict__ ranges) {
  int w = blockIdx.x * 256 + threadIdx.x;
  if (w > NW_AGG) return;
  if (w == NW_AGG) {
    ranges[w] = N_NODES;
    return;
  }
  long t = ((long)w * N_EDGES + NW_AGG - 1) / NW_AGG;
  int lo = 0, hi = N_NODES;
  while (lo < hi) {
    int mid = (lo + hi) >> 1;
    if ((long)offsets[mid] >= t) hi = mid;
    else lo = mid + 1;
  }
  ranges[w] = lo;
}

__global__ __launch_bounds__(256) void conv_h0(const int* __restrict__ node_ids,
                                               const float* __restrict__ emb,
                                               ushort_t* __restrict__ h0h) {
  long gid = (long)blockIdx.x * 256 + threadIdx.x;
  if (gid >= (long)N_NODES * HDIM) return;
  int n = (int)(gid >> 7);
  int o = (int)(gid & 127);
  h0h[gid] = f2h(emb[(long)node_ids[n] * HDIM + o]);
}

__global__ __launch_bounds__(256) void conv_w1(const float* __restrict__ W,
                                               ushort_t* __restrict__ Wh) {
  int idx = blockIdx.x * 256 + threadIdx.x;
  if (idx >= NREL * NBLK * 64) return;
  int rb = idx >> 6, i = (idx >> 3) & 7, o = idx & 7;
  int g = o >> 1, c = o & 1, ip = i >> 1, hi = i & 1;
  Wh[(((rb * 4 + g) * 2 + c) * 4 + ip) * 2 + hi] = f2h(W[idx]);
}

__global__ __launch_bounds__(256) void conv_w2(const float* __restrict__ W,
                                               ushort_t* __restrict__ Wh) {
  int idx = blockIdx.x * 256 + threadIdx.x;
  if (idx >= NREL * NBLK * 128) return;
  int rb = idx >> 7, i = (idx >> 4) & 7, o = idx & 15;
  int g = o >> 2, c = o & 3, ip = i >> 1, hi = i & 1;
  Wh[(((rb * 4 + g) * 4 + c) * 4 + ip) * 2 + hi] = f2h(W[idx]);
}

// ================= FALLBACK: gather-form aggregation ===========
__global__ __launch_bounds__(256, 4) void agg_layer1(
    const int4* __restrict__ rec, const int* __restrict__ offsets,
    const int* __restrict__ ranges, const ushort_t* __restrict__ h0h,
    const ushort_t* __restrict__ Wh, float* __restrict__ agg) {
  __shared__ __align__(16) ushort_t smem[4][4096];
  int w = blockIdx.x * 4 + (threadIdx.x >> 6);
  int l = threadIdx.x & 63;
  int wid = threadIdx.x >> 6;
  int lo = ranges[w], hi = ranges[w + 1];
  if (lo >= hi) return;
  const ushort_t* Wl = Wh + (size_t)l * 16;
  int hoff = (l >> 2) << 3;
  int estart = offsets[lo];
  int ecnt = offsets[hi] - estart;
  int cur = lo;
  int next_b = offsets[lo + 1];
  int e = estart;
  float ac0 = 0.f, ac1 = 0.f;
#define L1_FLUSH                                                               \
  {                                                                            \
    float2 res = {ac0, ac1};                                                   \
    *(float2*)(agg + (long)cur * HDIM + (l << 1)) = res;                       \
    ac0 = ac1 = 0.f;                                                           \
    ++cur;                                                                     \
    next_b = offsets[cur + 1];                                                 \
  }
  for (int c0 = 0; c0 < ecnt; c0 += 32) {
    int m = min(32, ecnt - c0);
    int4 r = make_int4(0, 0, 0, 0);
    if (l < m) r = rec[estart + c0 + l];
    STAGE_H32(h0h, smem[wid])
    for (int k = 0; k < m; ++k) {
      while (e == next_b) L1_FLUSH
      int wy_ = __shfl(r.y, k);
      float nn_ = __uint_as_float((uint_t)__shfl(r.z, k));
      const uint4* Wp_ = (const uint4*)(Wl + (size_t)wy_ * 1024);
      uint4 q0_ = Wp_[0], q1_ = Wp_[1];
      uint4 u = *(const uint4*)&smem[wid][(k << 7) + hoff];
      float p0 = 0.f, p1 = 0.f;
      FDOT2(p0, u.x, q0_.x) FDOT2(p0, u.y, q0_.y)
      FDOT2(p0, u.z, q0_.z) FDOT2(p0, u.w, q0_.w)
      FDOT2(p1, u.x, q1_.x) FDOT2(p1, u.y, q1_.y)
      FDOT2(p1, u.z, q1_.z) FDOT2(p1, u.w, q1_.w)
      ac0 = fmaf(p0, nn_, ac0);
      ac1 = fmaf(p1, nn_, ac1);
      ++e;
    }
  }
  while (cur < hi) {
    float2 res = {ac0, ac1};
    *(float2*)(agg + (long)cur * HDIM + (l << 1)) = res;
    ac0 = ac1 = 0.f;
    ++cur;
  }
#undef L1_FLUSH
}

__global__ __launch_bounds__(256, 4) void agg_layer2(
    const int4* __restrict__ rec, const int* __restrict__ offsets,
    const int* __restrict__ ranges, const ushort_t* __restrict__ h1h,
    const ushort_t* __restrict__ Wh, float* __restrict__ agg) {
  __shared__ __align__(16) ushort_t smem[4][4096];
  int w = blockIdx.x * 4 + (threadIdx.x >> 6);
  int l = threadIdx.x & 63;
  int wid = threadIdx.x >> 6;
  int lo = ranges[w], hi = ranges[w + 1];
  if (lo >= hi) return;
  const ushort_t* Wl = Wh + (size_t)l * 32;
  int hoff = (l >> 2) << 3;
  int estart = offsets[lo];
  int ecnt = offsets[hi] - estart;
  int cur = lo;
  int next_b = offsets[lo + 1];
  int e = estart;
  float ax = 0.f, ay = 0.f, az = 0.f, aw = 0.f;
#define L2_FLUSH                                                               \
  {                                                                            \
    float4 res = {ax, ay, az, aw};                                             \
    *(float4*)(agg + (long)cur * 256 + (l << 2)) = res;                        \
    ax = ay = az = aw = 0.f;                                                   \
    ++cur;                                                                     \
    next_b = offsets[cur + 1];                                                 \
  }
  for (int c0 = 0; c0 < ecnt; c0 += 32) {
    int m = min(32, ecnt - c0);
    int4 r = make_int4(0, 0, 0, 0);
    if (l < m) r = rec[estart + c0 + l];
    STAGE_H32(h1h, smem[wid])
    for (int k = 0; k < m; ++k) {
      while (e == next_b) L2_FLUSH
      int wy_ = __shfl(r.y, k);
      float nn_ = __uint_as_float((uint_t)__shfl(r.z, k));
      const uint4* Wp_ = (const uint4*)(Wl + (size_t)wy_ * 2048);
      uint4 q0_ = Wp_[0], q1_ = Wp_[1], q2_ = Wp_[2], q3_ = Wp_[3];
      uint4 u = *(const uint4*)&smem[wid][(k << 7) + hoff];
      float px = 0.f, py = 0.f, pz = 0.f, pw = 0.f;
      FDOT2(px, u.x, q0_.x) FDOT2(px, u.y, q0_.y)
      FDOT2(px, u.z, q0_.z) FDOT2(px, u.w, q0_.w)
      FDOT2(py, u.x, q1_.x) FDOT2(py, u.y, q1_.y)
      FDOT2(py, u.z, q1_.z) FDOT2(py, u.w, q1_.w)
      FDOT2(pz, u.x, q2_.x) FDOT2(pz, u.y, q2_.y)
      FDOT2(pz, u.z, q2_.z) FDOT2(pz, u.w, q2_.w)
      FDOT2(pw, u.x, q3_.x) FDOT2(pw, u.y, q3_.y)
      FDOT2(pw, u.z, q3_.z) FDOT2(pw, u.w, q3_.w)
      ax = fmaf(px, nn_, ax);
      ay = fmaf(py, nn_, ay);
      az = fmaf(pz, nn_, az);
      aw = fmaf(pw, nn_, aw);
      ++e;
    }
  }
  while (cur < hi) {
    float4 res = {ax, ay, az, aw};
    *(float4*)(agg + (long)cur * 256 + (l << 2)) = res;
    ax = ay = az = aw = 0.f;
    ++cur;
  }
#undef L2_FLUSH
}

// ================= MSG PATH: per-group relation-batched GEMM ==========
__global__ __launch_bounds__(256, 4) void msg_gemm1g(
    int g, const int4* __restrict__ rec2, const int* __restrict__ offB,
    const int* __restrict__ tileOffB, const ushort_t* __restrict__ h0h,
    const ushort_t* __restrict__ Wh, ushort_t* __restrict__ msg) {
  __shared__ __align__(16) ushort_t smem[4][2048];
  int tid_g = tileOffB[g * NREL] + blockIdx.x;
  if (tid_g >= tileOffB[(g + 1) * NREL]) return;
  int lo = g * NREL, hi = (g + 1) * NREL;
  while (lo + 1 < hi) {
    int mid = (lo + hi) >> 1;
    if (tileOffB[mid] <= tid_g) lo = mid;
    else hi = mid;
  }
  int b = lo;
  int rrel = b - g * NREL;
  int t = tid_g - tileOffB[b];
  int ebase = offB[b] + t * TILE_E;
  int m64 = offB[b + 1] - offB[b] - t * TILE_E;
  if (m64 > TILE_E) m64 = TILE_E;
  int wid = threadIdx.x >> 6, l = threadIdx.x & 63;
  int mw = m64 - wid * 16;
  mw = mw < 0 ? 0 : (mw > 16 ? 16 : mw);
  if (mw <= 0) return;
  const uint4* Wp = (const uint4*)(Wh + (size_t)rrel * 1024 + (size_t)l * 16);
  uint4 q0 = Wp[0], q1 = Wp[1];
  int4 r2 = make_int4(0, 0, 0, 0);
  if (l < mw) r2 = rec2[ebase + wid * 16 + l];
  STAGE16R(h0h, smem[wid], r2, mw, l)
  int hoff = (l >> 2) << 3;
  for (int k = 0; k < mw; ++k) {
    int p = __shfl(r2.y, k);
    float nn = __uint_as_float((uint_t)__shfl(r2.z, k));
    uint4 u = *(const uint4*)&smem[wid][(k << 7) + hoff];
    float p0 = 0.f, p1 = 0.f;
    FDOT2(p0, u.x, q0.x) FDOT2(p0, u.y, q0.y)
    FDOT2(p0, u.z, q0.z) FDOT2(p0, u.w, q0.w)
    FDOT2(p1, u.x, q1.x) FDOT2(p1, u.y, q1.y)
    FDOT2(p1, u.z, q1.z) FDOT2(p1, u.w, q1.w)
    p0 *= nn;
    p1 *= nn;
    uint_t ov = (uint_t)f2h(p0) | ((uint_t)f2h(p1) << 16);
    *(uint_t*)&msg[(long)p * 128 + (l << 1)] = ov;
  }
}

__global__ __launch_bounds__(256, 4) void msg_gemm2g(
    int g, const int4* __restrict__ rec2, const int* __restrict__ offB,
    const int* __restrict__ tileOffB, const ushort_t* __restrict__ h1h,
    const ushort_t* __restrict__ Wh, ushort_t* __restrict__ msg) {
  __shared__ __align__(16) ushort_t smem[4][2048];
  int tid_g = tileOffB[g * NREL] + blockIdx.x;
  if (tid_g >= tileOffB[(g + 1) * NREL]) return;
  int lo = g * NREL, hi = (g + 1) * NREL;
  while (lo + 1 < hi) {
    int mid = (lo + hi) >> 1;
    if (tileOffB[mid] <= tid_g) lo = mid;
    else hi = mid;
  }
  int b = lo;
  int rrel = b - g * NREL;
  int t = tid_g - tileOffB[b];
  int ebase = offB[b] + t * TILE_E;
  int m64 = offB[b + 1] - offB[b] - t * TILE_E;
  if (m64 > TILE_E) m64 = TILE_E;
  int wid = threadIdx.x >> 6, l = threadIdx.x & 63;
  int mw = m64 - wid * 16;
  mw = mw < 0 ? 0 : (mw > 16 ? 16 : mw);
  if (mw <= 0) return;
  const uint4* Wp = (const uint4*)(Wh + (size_t)rrel * 2048 + (size_t)l * 32);
  uint4 q0 = Wp[0], q1 = Wp[1], q2 = Wp[2], q3 = Wp[3];
  int4 r2 = make_int4(0, 0, 0, 0);
  if (l < mw) r2 = rec2[ebase + wid * 16 + l];
  STAGE16R(h1h, smem[wid], r2, mw, l)
  int hoff = (l >> 2) << 3;
  for (int k = 0; k < mw; ++k) {
    int p = __shfl(r2.y, k);
    float nn = __uint_as_float((uint_t)__shfl(r2.z, k));
    uint4 u = *(const uint4*)&smem[wid][(k << 7) + hoff];
    float px = 0.f, py = 0.f, pz = 0.f, pw = 0.f;
    FDOT2(px, u.x, q0.x) FDOT2(px, u.y, q0.y)
    FDOT2(px, u.z, q0.z) FDOT2(px, u.w, q0.w)
    FDOT2(py, u.x, q1.x) FDOT2(py, u.y, q1.y)
    FDOT2(py, u.z, q1.z) FDOT2(py, u.w, q1.w)
    FDOT2(pz, u.x, q2.x) FDOT2(pz, u.y, q2.y)
    FDOT2(pz, u.z, q2.z) FDOT2(pz, u.w, q2.w)
    FDOT2(pw, u.x, q3.x) FDOT2(pw, u.y, q3.y)
    FDOT2(pw, u.z, q3.z) FDOT2(pw, u.w, q3.w)
    px *= nn;
    py *= nn;
    pz *= nn;
    pw *= nn;
    uint2 ov;
    ov.x = (uint_t)f2h(px) | ((uint_t)f2h(py) << 16);
    ov.y = (uint_t)f2h(pz) | ((uint_t)f2h(pw) << 16);
    *(uint2*)&msg[(long)p * 256 + (l << 2)] = ov;
  }
}

// ========== Node layer 1 (fallback: agg input) ==========
__global__ __launch_bounds__(256) void node_layer1(
    const ushort_t* __restrict__ h0h, const float* __restrict__ loop1,
    const float* __restrict__ agg1, const float* __restrict__ bias,
    ushort_t* __restrict__ h1h) {
  __shared__ __align__(8) ushort_t Lh[128 * 130];
  __shared__ __align__(8) ushort_t hs[NT * 128];
  int tid = threadIdx.x;
  for (int t = 0; t < 64; ++t) {
    int flat = t * 256 + tid;
    int i = flat >> 7, o = flat & 127;
    Lh[o * 130 + i] = f2h(loop1[i * 128 + o]);
  }
  __syncthreads();
  int o = tid & 127;
  int g = tid >> 7;
  for (int grp = blockIdx.x; grp < N_NODES / NT; grp += gridDim.x) {
    int n0 = grp * NT;
    __syncthreads();
    for (int t = 0; t < 4; ++t) {
      int flat = t * 256 + tid;
      int j = flat >> 7, i = flat & 127;
      hs[j * 128 + i] = h0h[(long)(n0 + j) * 128 + i];
    }
    __syncthreads();
    float acc[4] = {0.f, 0.f, 0.f, 0.f};
    const ushort_t* Lo = &Lh[o * 130];
    const ushort_t* hb = &hs[(g * 4) * 128];
    for (int i = 0; i < 128; i += 4) {
      uint_t lv01 = *(const uint_t*)&Lo[i];
      uint_t lv23 = *(const uint_t*)&Lo[i + 2];
#pragma unroll
      for (int j = 0; j < 4; ++j) {
        uint2 hj = *(const uint2*)&hb[j * 128 + i];
        FDOT2(acc[j], hj.x, lv01)
        FDOT2(acc[j], hj.y, lv23)
      }
    }
    float bo = bias[o];
#pragma unroll
    for (int j = 0; j < 4; ++j) {
      int n = n0 + g * 4 + j;
      float v = acc[j] + bo + agg1[(long)n * 128 + o];
      h1h[(long)n * 128 + o] = f2h(fmaxf(v, 0.f));
    }
  }
}

// ========== Node layer 2 fused (fallback: agg input) ==========
__global__ __launch_bounds__(256) void node_layer2f(
    const ushort_t* __restrict__ h1h, const float* __restrict__ loop2,
    const float* __restrict__ agg2, const float* __restrict__ bias2,
    const float* __restrict__ eps, float* __restrict__ out) {
  __shared__ __align__(8) ushort_t Lh[256 * 130];
  __shared__ __align__(8) ushort_t hs[NT * 128];
  __shared__ float spbuf[NT * 128];
  int o = threadIdx.x;
  for (int t = 0; t < 128; ++t) {
    int flat = t * 256 + o;
    int i = flat >> 8, c = flat & 255;
    Lh[c * 130 + i] = f2h(loop2[i * 256 + c]);
  }
  __syncthreads();
  for (int grp = blockIdx.x; grp < N_NODES / NT; grp += gridDim.x) {
    int n0 = grp * NT;
    __syncthreads();
    for (int t = 0; t < 4; ++t) {
      int flat = t * 256 + o;
      int j = flat >> 7, i = flat & 127;
      hs[j * 128 + i] = h1h[(long)(n0 + j) * 128 + i];
    }
    __syncthreads();
    float acc[NT] = {0.f, 0.f, 0.f, 0.f, 0.f, 0.f, 0.f, 0.f};
    const ushort_t* Lo = &Lh[o * 130];
    for (int i = 0; i < 128; i += 4) {
      uint_t lv01 = *(const uint_t*)&Lo[i];
      uint_t lv23 = *(const uint_t*)&Lo[i + 2];
#pragma unroll
      for (int j = 0; j < NT; ++j) {
        uint2 hj = *(const uint2*)&hs[j * 128 + i];
        FDOT2(acc[j], hj.x, lv01)
        FDOT2(acc[j], hj.y, lv23)
      }
    }
    float bo = bias2[o];
    if (o >= 128) {
      int oc = o - 128;
#pragma unroll
      for (int j = 0; j < NT; ++j) {
        float hv = acc[j] + bo + agg2[(long)(n0 + j) * 256 + o];
        float sp = fmaxf(hv, 0.f) + log1pf(expf(-fabsf(hv)));
        spbuf[j * 128 + oc] = sqrtf(sp + 1e-8f);
      }
    }
    __syncthreads();
    if (o < 128) {
#pragma unroll
      for (int j = 0; j < NT; ++j) {
        float mval = acc[j] + bo + agg2[(long)(n0 + j) * 256 + o];
        long off2_ = (long)(n0 + j) * 128 + o;
        out[off2_] = mval + spbuf[j * 128 + o] * eps[off2_];
      }
    }
  }
}

// ========== Node layer 1 (msg path, per group) ==========
__global__ __launch_bounds__(256) void node_layer1mg(
    int g, const ushort_t* __restrict__ h0h, const float* __restrict__ loop1,
    const ushort_t* __restrict__ msg1, const int* __restrict__ offsets,
    const float* __restrict__ bias, ushort_t* __restrict__ h1h) {
  __shared__ __align__(8) ushort_t Lh[128 * 130];
  __shared__ __align__(8) ushort_t hs[NT * 128];
  int tid = threadIdx.x;
  for (int t = 0; t < 64; ++t) {
    int flat = t * 256 + tid;
    int i = flat >> 7, o = flat & 127;
    Lh[o * 130 + i] = f2h(loop1[i * 128 + o]);
  }
  int ebg = offsets[g * GSZ];
  __syncthreads();
  int o = tid & 127;
  int gg = tid >> 7;
  int n0 = g * GSZ + blockIdx.x * NT;
  for (int t = 0; t < 4; ++t) {
    int flat = t * 256 + tid;
    int j = flat >> 7, i = flat & 127;
    hs[j * 128 + i] = h0h[(long)(n0 + j) * 128 + i];
  }
  __syncthreads();
  float acc[4] = {0.f, 0.f, 0.f, 0.f};
  const ushort_t* Lo = &Lh[o * 130];
  const ushort_t* hb = &hs[(gg * 4) * 128];
  for (int i = 0; i < 128; i += 4) {
    uint_t lv01 = *(const uint_t*)&Lo[i];
    uint_t lv23 = *(const uint_t*)&Lo[i + 2];
#pragma unroll
    for (int j = 0; j < 4; ++j) {
      uint2 hj = *(const uint2*)&hb[j * 128 + i];
      FDOT2(acc[j], hj.x, lv01)
      FDOT2(acc[j], hj.y, lv23)
    }
  }
  float bo = bias[o];
#pragma unroll
  for (int j = 0; j < 4; ++j) {
    int n = n0 + gg * 4 + j;
    int s = offsets[n] - ebg, eN = offsets[n + 1] - ebg;
    float ag = 0.f;
    for (int k = s; k < eN; ++k) ag += h2f(msg1[(long)k * 128 + o]);
    float v = acc[j] + bo + ag;
    h1h[(long)n * 128 + o] = f2h(fmaxf(v, 0.f));
  }
}

// ========== Node layer 2 fused (msg path, per group) ==========
__global__ __launch_bounds__(256) void node_layer2fmg(
    int g, const ushort_t* __restrict__ h1h, const float* __restrict__ loop2,
    const ushort_t* __restrict__ msg2, const int* __restrict__ offsets,
    const float* __restrict__ bias2, const float* __restrict__ eps,
    float* __restrict__ out) {
  __shared__ __align__(8) ushort_t Lh[256 * 130];
  __shared__ __align__(8) ushort_t hs[NT * 128];
  __shared__ float spbuf[NT * 128];
  int o = threadIdx.x;
  for (int t = 0; t < 128; ++t) {
    int flat = t * 256 + o;
    int i = flat >> 8, c = flat & 255;
    Lh[c * 130 + i] = f2h(loop2[i * 256 + c]);
  }
  int ebg = offsets[g * GSZ];
  __syncthreads();
  int n0 = g * GSZ + blockIdx.x * NT;
  for (int t = 0; t < 4; ++t) {
    int flat = t * 256 + o;
    int j = flat >> 7, i = flat & 127;
    hs[j * 128 + i] = h1h[(long)(n0 + j) * 128 + i];
  }
  __syncthreads();
  float acc[NT] = {0.f, 0.f, 0.f, 0.f, 0.f, 0.f, 0.f, 0.f};
  const ushort_t* Lo = &Lh[o * 130];
  for (int i = 0; i < 128; i += 4) {
    uint_t lv01 = *(const uint_t*)&Lo[i];
    uint_t lv23 = *(const uint_t*)&Lo[i + 2];
#pragma unroll
    for (int j = 0; j < NT; ++j) {
      uint2 hj = *(const uint2*)&hs[j * 128 + i];
      FDOT2(acc[j], hj.x, lv01)
      FDOT2(acc[j], hj.y, lv23)
    }
  }
  float bo = bias2[o];
#pragma unroll
  for (int j = 0; j < NT; ++j) {
    int n = n0 + j;
    int s = offsets[n] - ebg, eN = offsets[n + 1] - ebg;
    float ag = 0.f;
    for (int k = s; k < eN; ++k) ag += h2f(msg2[(long)k * 256 + o]);
    acc[j] += bo + ag;
  }
  if (o >= 128) {
    int oc = o - 128;
#pragma unroll
    for (int j = 0; j < NT; ++j) {
      float hv = acc[j];
      float sp = fmaxf(hv, 0.f) + log1pf(expf(-fabsf(hv)));
      spbuf[j * 128 + oc] = sqrtf(sp + 1e-8f);
    }
  }
  __syncthreads();
  if (o < 128) {
#pragma unroll
    for (int j = 0; j < NT; ++j) {
      long off2_ = (long)(n0 + j) * 128 + o;
      out[off2_] = acc[j] + spbuf[j * 128 + o] * eps[off2_];
    }
  }
}

extern "C" void kernel_launch(void* const* d_in, const int* in_sizes, int n_in,
                              void* d_out, int out_size, void* d_ws, size_t ws_size,
                              hipStream_t stream) {
  const int* node_ids = (const int*)d_in[0];
  const int* src      = (const int*)d_in[1];
  const int* dst      = (const int*)d_in[2];
  const int* etype    = (const int*)d_in[3];
  const float* norm   = (const float*)d_in[4];
  const float* emb    = (const float*)d_in[5];
  const float* W1     = (const float*)d_in[6];
  const float* loop1  = (const float*)d_in[7];
  const float* b1     = (const float*)d_in[8];
  const float* W2     = (const float*)d_in[9];
  const float* loop2  = (const float*)d_in[10];
  const float* b2     = (const float*)d_in[11];
  const float* eps    = (const float*)d_in[12];
  float* out = (float*)d_out;

  char* ws = (char*)d_ws;
  size_t off = 0;
  int* deg      = (int*)(ws + off); off += (size_t)N_NODES * 4;
  int* cursor   = (int*)(ws + off); off += (size_t)N_NODES * 4;
  int* cntB     = (int*)(ws + off); off += (size_t)NBUCK * 4;
  int* curB     = (int*)(ws + off); off += (size_t)NBUCK * 4;
  int* offsets  = (int*)(ws + off); off += (size_t)(N_NODES + 1) * 4;
  int* offB     = (int*)(ws + off); off += (size_t)(NBUCK + 1) * 4;
  int* tcB      = (int*)(ws + off); off += (size_t)NBUCK * 4;
  int* tileOffB = (int*)(ws + off); off += (size_t)(NBUCK + 1) * 4;
  int* ranges   = (int*)(ws + off); off += (size_t)(NW_AGG + 1) * 4;
  off = (off + 15) & ~(size_t)15;
  int4* rec     = (int4*)(ws + off); off += (size_t)N_EDGES * 16;
  ushort_t* h0h = (ushort_t*)(ws + off); off += (size_t)N_NODES * HDIM * 2;
  ushort_t* h1h = (ushort_t*)(ws + off); off += (size_t)N_NODES * HDIM * 2;
  ushort_t* Wh1 = (ushort_t*)(ws + off); off += (size_t)NREL * NBLK * 64 * 2;
  ushort_t* Wh2 = (ushort_t*)(ws + off); off += (size_t)NREL * NBLK * 128 * 2;
  off = (off + 15) & ~(size_t)15;
  size_t tail = off;
  size_t need_c = tail + (size_t)MAXE_G * 256 * 2;   // msg buffer (90 MB)
  bool use_c = (ws_size >= need_c);

  // ---- common build ----
  hipMemsetAsync(deg, 0, ((size_t)2 * N_NODES + 2 * NBUCK) * 4, stream);
  hist_deg<<<(N_EDGES + 255) / 256, 256, 0, stream>>>(dst, deg);
  conv_w1<<<(NREL * NBLK * 64 + 255) / 256, 256, 0, stream>>>(W1, Wh1);
  conv_w2<<<(NREL * NBLK * 128 + 255) / 256, 256, 0, stream>>>(W2, Wh2);
  scanN<<<1, 1024, 0, stream>>>(deg, offsets, N_NODES);
  conv_h0<<<(N_NODES * HDIM + 255) / 256, 256, 0, stream>>>(node_ids, emb, h0h);

  if (use_c) {
    ushort_t* msg = (ushort_t*)(ws + tail);
    const int T_G = MAXE_G / TILE_E + NREL;  // per-group tile grid bound
    hist_grel<<<(N_EDGES + 255) / 256, 256, 0, stream>>>(dst, etype, cntB);
    scanN<<<1, 1024, 0, stream>>>(cntB, offB, NBUCK);
    calc_tc<<<(NBUCK + 255) / 256, 256, 0, stream>>>(cntB, tcB);
    scanN<<<1, 1024, 0, stream>>>(tcB, tileOffB, NBUCK);
    scatter2g<<<(N_EDGES + 255) / 256, 256, 0, stream>>>(
        src, dst, etype, norm, offsets, cursor, offB, curB, rec);
    for (int g = 0; g < NG; ++g) {
      msg_gemm1g<<<T_G, 256, 0, stream>>>(g, rec, offB, tileOffB, h0h, Wh1, msg);
      node_layer1mg<<<GSZ / NT, 256, 0, stream>>>(g, h0h, loop1, msg, offsets,
                                                  b1, h1h);
    }
    for (int g = 0; g < NG; ++g) {
      msg_gemm2g<<<T_G, 256, 0, stream>>>(g, rec, offB, tileOffB, h1h, Wh2, msg);
      node_layer2fmg<<<GSZ / NT, 256, 0, stream>>>(g, h1h, loop2, msg, offsets,
                                                   b2, eps, out);
    }
  } else {
    float* agg2 = (float*)(ws + tail);
    float* agg1 = out;  // dead before node_layer2f writes out
    calc_ranges<<<(NW_AGG + 256) / 256, 256, 0, stream>>>(offsets, ranges);
    scatter_rec<<<(N_EDGES + 255) / 256, 256, 0, stream>>>(src, dst, etype, norm,
                                                           offsets, cursor, rec);
    agg_layer1<<<NW_AGG / 4, 256, 0, stream>>>(rec, offsets, ranges, h0h, Wh1, agg1);
    node_layer1<<<1024, 256, 0, stream>>>(h0h, loop1, agg1, b1, h1h);
    agg_layer2<<<NW_AGG / 4, 256, 0, stream>>>(rec, offsets, ranges, h1h, Wh2, agg2);
    node_layer2f<<<512, 256, 0, stream>>>(h1h, loop2, agg2, b2, eps, out);
  }
}

// Round 20
// 4793.314 us; speedup vs baseline: 1.0222x; 1.0222x over previous
//
#include <hip/hip_runtime.h>
#include <math.h>

#define N_NODES 100000
#define N_EDGES 1600000
#define HDIM 128
#define NBLK 16
#define NREL 200
#define NW_AGG 8192   // balanced waves (fallback path)
#define TILE_E 64     // edges per block in msg GEMM
#define NT 8          // node-tile for node kernels
#define NG 10         // node groups (msg path)
#define GSZ 10000     // nodes per group
#define NBUCK (NG * NREL)
#define MAXE_G 176000 // max edges per group (mean 160K, fixed dataset)

typedef unsigned short ushort_t;
typedef unsigned int uint_t;
typedef _Float16 h2 __attribute__((ext_vector_type(2)));

__device__ __forceinline__ ushort_t f2h(float f) {
  _Float16 h = (_Float16)f;
  return __builtin_bit_cast(unsigned short, h);
}
__device__ __forceinline__ float h2f(ushort_t b) {
  return (float)__builtin_bit_cast(_Float16, b);
}

#if defined(__has_builtin) && __has_builtin(__builtin_amdgcn_fdot2)
#define FDOT2(accv, au, bu)                                                    \
  accv = __builtin_amdgcn_fdot2(__builtin_bit_cast(h2, au),                    \
                                __builtin_bit_cast(h2, bu), accv, false);
#else
#define FDOT2(accv, au, bu)                                                    \
  {                                                                            \
    h2 av_ = __builtin_bit_cast(h2, au);                                       \
    h2 bv_ = __builtin_bit_cast(h2, bu);                                       \
    accv = fmaf((float)av_[0], (float)bv_[0], accv);                           \
    accv = fmaf((float)av_[1], (float)bv_[1], accv);                           \
  }
#endif

#if defined(__has_builtin) && __has_builtin(__builtin_amdgcn_global_load_lds)
#define HAVE_GLL 1
#else
#define HAVE_GLL 0
#endif

// Stage 32 h-rows (8KB) into wave slab (fallback agg path).
#if HAVE_GLL
#define STAGE_H32(HSRC, SMEMW)                                                 \
  {                                                                            \
    _Pragma("unroll") for (int i_ = 0; i_ < 8; ++i_) {                         \
      int ei_ = (i_ << 2) + (l >> 4);                                          \
      if (ei_ >= m) ei_ = m - 1;                                               \
      int ss_ = __shfl(r.x, ei_);                                              \
      const ushort_t* gsrc_ = HSRC + ((long)ss_ << 7) + ((l & 15) << 3);       \
      __builtin_amdgcn_global_load_lds(                                        \
          (const __attribute__((address_space(1))) unsigned int*)gsrc_,        \
          (__attribute__((address_space(3))) unsigned int*)&SMEMW[i_ << 9],    \
          16, 0, 0);                                                           \
    }                                                                          \
    asm volatile("s_waitcnt vmcnt(0)" ::: "memory");                           \
  }
#else
#define STAGE_H32(HSRC, SMEMW)                                                 \
  {                                                                            \
    _Pragma("unroll") for (int i_ = 0; i_ < 8; ++i_) {                         \
      int ei_ = (i_ << 2) + (l >> 4);                                          \
      if (ei_ >= m) ei_ = m - 1;                                               \
      int ss_ = __shfl(r.x, ei_);                                              \
      const ushort_t* gsrc_ = HSRC + ((long)ss_ << 7) + ((l & 15) << 3);       \
      uint4 t_ = *(const uint4*)gsrc_;                                         \
      *(uint4*)&SMEMW[(i_ << 9) + (l << 3)] = t_;                              \
    }                                                                          \
  }
#endif

// Stage up to 16 h-rows (4KB) into wave slab (msg GEMM path).
#if HAVE_GLL
#define STAGE16R(HSRC, SLABP, RR, MM, LL)                                      \
  {                                                                            \
    _Pragma("unroll") for (int i_ = 0; i_ < 4; ++i_) {                         \
      int ei_ = (i_ << 2) + (LL >> 4);                                         \
      if (ei_ >= MM) ei_ = MM - 1;                                             \
      int ss_ = __shfl(RR.x, ei_);                                             \
      const ushort_t* gsrc_ = HSRC + ((long)ss_ << 7) + ((LL & 15) << 3);      \
      __builtin_amdgcn_global_load_lds(                                        \
          (const __attribute__((address_space(1))) unsigned int*)gsrc_,        \
          (__attribute__((address_space(3))) unsigned int*)&SLABP[i_ << 9],    \
          16, 0, 0);                                                           \
    }                                                                          \
    asm volatile("s_waitcnt vmcnt(0)" ::: "memory");                           \
  }
#else
#define STAGE16R(HSRC, SLABP, RR, MM, LL)                                      \
  {                                                                            \
    _Pragma("unroll") for (int i_ = 0; i_ < 4; ++i_) {                         \
      int ei_ = (i_ << 2) + (LL >> 4);                                         \
      if (ei_ >= MM) ei_ = MM - 1;                                             \
      int ss_ = __shfl(RR.x, ei_);                                             \
      const ushort_t* gsrc_ = HSRC + ((long)ss_ << 7) + ((LL & 15) << 3);      \
      uint4 t_ = *(const uint4*)gsrc_;                                         \
      *(uint4*)&SLABP[(i_ << 9) + (LL << 3)] = t_;                             \
    }                                                                          \
  }
#endif

// ================= build kernels =================
__global__ __launch_bounds__(256) void hist_deg(const int* __restrict__ dst,
                                                int* __restrict__ deg) {
  int e = blockIdx.x * 256 + threadIdx.x;
  if (e < N_EDGES) atomicAdd(&deg[dst[e]], 1);
}

__global__ __launch_bounds__(256) void hist_grel(const int* __restrict__ dst,
                                                 const int* __restrict__ etype,
                                                 int* __restrict__ cntB) {
  int e = blockIdx.x * 256 + threadIdx.x;
  if (e >= N_EDGES) return;
  int b = (dst[e] / GSZ) * NREL + etype[e];
  atomicAdd(&cntB[b], 1);
}

// generalized single-block exclusive scan over n elems; writes out[n]=total
__global__ __launch_bounds__(1024) void scanN(const int* __restrict__ in,
                                              int* __restrict__ out, int n) {
  __shared__ int wsum[16];
  __shared__ int carry_s;
  int tid = threadIdx.x, lane = tid & 63, wid = tid >> 6;
  if (tid == 0) carry_s = 0;
  __syncthreads();
  for (int base = 0; base < n; base += 1024) {
    int i = base + tid;
    int v = (i < n) ? in[i] : 0;
    int x = v;
#pragma unroll
    for (int s = 1; s < 64; s <<= 1) {
      int t = __shfl_up(x, s);
      if (lane >= s) x += t;
    }
    if (lane == 63) wsum[wid] = x;
    __syncthreads();
    if (wid == 0) {
      int y = (lane < 16) ? wsum[lane] : 0;
#pragma unroll
      for (int s = 1; s < 16; s <<= 1) {
        int t = __shfl_up(y, s);
        if (lane >= s) y += t;
      }
      if (lane < 16) wsum[lane] = y;
    }
    __syncthreads();
    int carry = carry_s;
    int wbase = (wid > 0) ? wsum[wid - 1] : 0;
    if (i < n) out[i] = carry + wbase + (x - v);
    __syncthreads();
    if (tid == 0) carry_s = carry + wsum[15];
    __syncthreads();
  }
  if (threadIdx.x == 0) out[n] = carry_s;
}

__global__ __launch_bounds__(256) void calc_tc(const int* __restrict__ cntB,
                                               int* __restrict__ tcB) {
  int i = blockIdx.x * 256 + threadIdx.x;
  if (i < NBUCK) tcB[i] = (cntB[i] + TILE_E - 1) / TILE_E;
}

// fallback: dst-CSR records {src, etype, norm}
__global__ __launch_bounds__(256) void scatter_rec(
    const int* __restrict__ src, const int* __restrict__ dst,
    const int* __restrict__ etype, const float* __restrict__ norm,
    const int* __restrict__ offsets, int* __restrict__ cursor,
    int4* __restrict__ rec) {
  int e = blockIdx.x * 256 + threadIdx.x;
  if (e >= N_EDGES) return;
  int d = dst[e];
  int pos = offsets[d] + atomicAdd(&cursor[d], 1);
  rec[pos] = make_int4(src[e], etype[e], __float_as_int(norm[e]), 0);
}

// msg path: group-major relation-sorted records {src, group-local csr pos, norm}
__global__ __launch_bounds__(256) void scatter2g(
    const int* __restrict__ src, const int* __restrict__ dst,
    const int* __restrict__ etype, const float* __restrict__ norm,
    const int* __restrict__ offsets, int* __restrict__ cursor,
    const int* __restrict__ offB, int* __restrict__ curB,
    int4* __restrict__ rec2) {
  int e = blockIdx.x * 256 + threadIdx.x;
  if (e >= N_EDGES) return;
  int d = dst[e];
  int pc = offsets[d] + atomicAdd(&cursor[d], 1);
  int g = d / GSZ;
  int b = g * NREL + etype[e];
  int pr = offB[b] + atomicAdd(&curB[b], 1);
  int pcl = pc - offsets[g * GSZ];  // group-local csr position
  rec2[pr] = make_int4(src[e], pcl, __float_as_int(norm[e]), 0);
}

__global__ __launch_bounds__(256) void calc_ranges(const int* __restrict__ offsets,
                                                   int* __restrict__ ranges) {
  int w = blockIdx.x * 256 + threadIdx.x;
  if (w > NW_AGG) return;
  if (w == NW_AGG) {
    ranges[w] = N_NODES;
    return;
  }
  long t = ((long)w * N_EDGES + NW_AGG - 1) / NW_AGG;
  int lo = 0, hi = N_NODES;
  while (lo < hi) {
    int mid = (lo + hi) >> 1;
    if ((long)offsets[mid] >= t) hi = mid;
    else lo = mid + 1;
  }
  ranges[w] = lo;
}

__global__ __launch_bounds__(256) void conv_h0(const int* __restrict__ node_ids,
                                               const float* __restrict__ emb,
                                               ushort_t* __restrict__ h0h) {
  long gid = (long)blockIdx.x * 256 + threadIdx.x;
  if (gid >= (long)N_NODES * HDIM) return;
  int n = (int)(gid >> 7);
  int o = (int)(gid & 127);
  h0h[gid] = f2h(emb[(long)node_ids[n] * HDIM + o]);
}

__global__ __launch_bounds__(256) void conv_w1(const float* __restrict__ W,
                                               ushort_t* __restrict__ Wh) {
  int idx = blockIdx.x * 256 + threadIdx.x;
  if (idx >= NREL * NBLK * 64) return;
  int rb = idx >> 6, i = (idx >> 3) & 7, o = idx & 7;
  int g = o >> 1, c = o & 1, ip = i >> 1, hi = i & 1;
  Wh[(((rb * 4 + g) * 2 + c) * 4 + ip) * 2 + hi] = f2h(W[idx]);
}

__global__ __launch_bounds__(256) void conv_w2(const float* __restrict__ W,
                                               ushort_t* __restrict__ Wh) {
  int idx = blockIdx.x * 256 + threadIdx.x;
  if (idx >= NREL * NBLK * 128) return;
  int rb = idx >> 7, i = (idx >> 4) & 7, o = idx & 15;
  int g = o >> 2, c = o & 3, ip = i >> 1, hi = i & 1;
  Wh[(((rb * 4 + g) * 4 + c) * 4 + ip) * 2 + hi] = f2h(W[idx]);
}

// loop1 (128x128) fp32 -> f16 transposed [o][i]
__global__ __launch_bounds__(256) void conv_l1t(const float* __restrict__ L,
                                                ushort_t* __restrict__ Lt) {
  int idx = blockIdx.x * 256 + threadIdx.x;
  if (idx >= 128 * 128) return;
  int i = idx >> 7, o = idx & 127;
  Lt[o * 128 + i] = f2h(L[i * 128 + o]);
}

// loop2 (128x256) fp32 -> f16 transposed [c][i]
__global__ __launch_bounds__(256) void conv_l2t(const float* __restrict__ L,
                                                ushort_t* __restrict__ Lt) {
  int idx = blockIdx.x * 256 + threadIdx.x;
  if (idx >= 128 * 256) return;
  int i = idx >> 8, c = idx & 255;
  Lt[c * 128 + i] = f2h(L[i * 256 + c]);
}

// ================= FALLBACK: gather-form aggregation ===========
__global__ __launch_bounds__(256, 4) void agg_layer1(
    const int4* __restrict__ rec, const int* __restrict__ offsets,
    const int* __restrict__ ranges, const ushort_t* __restrict__ h0h,
    const ushort_t* __restrict__ Wh, float* __restrict__ agg) {
  __shared__ __align__(16) ushort_t smem[4][4096];
  int w = blockIdx.x * 4 + (threadIdx.x >> 6);
  int l = threadIdx.x & 63;
  int wid = threadIdx.x >> 6;
  int lo = ranges[w], hi = ranges[w + 1];
  if (lo >= hi) return;
  const ushort_t* Wl = Wh + (size_t)l * 16;
  int hoff = (l >> 2) << 3;
  int estart = offsets[lo];
  int ecnt = offsets[hi] - estart;
  int cur = lo;
  int next_b = offsets[lo + 1];
  int e = estart;
  float ac0 = 0.f, ac1 = 0.f;
#define L1_FLUSH                                                               \
  {                                                                            \
    float2 res = {ac0, ac1};                                                   \
    *(float2*)(agg + (long)cur * HDIM + (l << 1)) = res;                       \
    ac0 = ac1 = 0.f;                                                           \
    ++cur;                                                                     \
    next_b = offsets[cur + 1];                                                 \
  }
  for (int c0 = 0; c0 < ecnt; c0 += 32) {
    int m = min(32, ecnt - c0);
    int4 r = make_int4(0, 0, 0, 0);
    if (l < m) r = rec[estart + c0 + l];
    STAGE_H32(h0h, smem[wid])
    for (int k = 0; k < m; ++k) {
      while (e == next_b) L1_FLUSH
      int wy_ = __shfl(r.y, k);
      float nn_ = __uint_as_float((uint_t)__shfl(r.z, k));
      const uint4* Wp_ = (const uint4*)(Wl + (size_t)wy_ * 1024);
      uint4 q0_ = Wp_[0], q1_ = Wp_[1];
      uint4 u = *(const uint4*)&smem[wid][(k << 7) + hoff];
      float p0 = 0.f, p1 = 0.f;
      FDOT2(p0, u.x, q0_.x) FDOT2(p0, u.y, q0_.y)
      FDOT2(p0, u.z, q0_.z) FDOT2(p0, u.w, q0_.w)
      FDOT2(p1, u.x, q1_.x) FDOT2(p1, u.y, q1_.y)
      FDOT2(p1, u.z, q1_.z) FDOT2(p1, u.w, q1_.w)
      ac0 = fmaf(p0, nn_, ac0);
      ac1 = fmaf(p1, nn_, ac1);
      ++e;
    }
  }
  while (cur < hi) {
    float2 res = {ac0, ac1};
    *(float2*)(agg + (long)cur * HDIM + (l << 1)) = res;
    ac0 = ac1 = 0.f;
    ++cur;
  }
#undef L1_FLUSH
}

__global__ __launch_bounds__(256, 4) void agg_layer2(
    const int4* __restrict__ rec, const int* __restrict__ offsets,
    const int* __restrict__ ranges, const ushort_t* __restrict__ h1h,
    const ushort_t* __restrict__ Wh, float* __restrict__ agg) {
  __shared__ __align__(16) ushort_t smem[4][4096];
  int w = blockIdx.x * 4 + (threadIdx.x >> 6);
  int l = threadIdx.x & 63;
  int wid = threadIdx.x >> 6;
  int lo = ranges[w], hi = ranges[w + 1];
  if (lo >= hi) return;
  const ushort_t* Wl = Wh + (size_t)l * 32;
  int hoff = (l >> 2) << 3;
  int estart = offsets[lo];
  int ecnt = offsets[hi] - estart;
  int cur = lo;
  int next_b = offsets[lo + 1];
  int e = estart;
  float ax = 0.f, ay = 0.f, az = 0.f, aw = 0.f;
#define L2_FLUSH                                                               \
  {                                                                            \
    float4 res = {ax, ay, az, aw};                                             \
    *(float4*)(agg + (long)cur * 256 + (l << 2)) = res;                        \
    ax = ay = az = aw = 0.f;                                                   \
    ++cur;                                                                     \
    next_b = offsets[cur + 1];                                                 \
  }
  for (int c0 = 0; c0 < ecnt; c0 += 32) {
    int m = min(32, ecnt - c0);
    int4 r = make_int4(0, 0, 0, 0);
    if (l < m) r = rec[estart + c0 + l];
    STAGE_H32(h1h, smem[wid])
    for (int k = 0; k < m; ++k) {
      while (e == next_b) L2_FLUSH
      int wy_ = __shfl(r.y, k);
      float nn_ = __uint_as_float((uint_t)__shfl(r.z, k));
      const uint4* Wp_ = (const uint4*)(Wl + (size_t)wy_ * 2048);
      uint4 q0_ = Wp_[0], q1_ = Wp_[1], q2_ = Wp_[2], q3_ = Wp_[3];
      uint4 u = *(const uint4*)&smem[wid][(k << 7) + hoff];
      float px = 0.f, py = 0.f, pz = 0.f, pw = 0.f;
      FDOT2(px, u.x, q0_.x) FDOT2(px, u.y, q0_.y)
      FDOT2(px, u.z, q0_.z) FDOT2(px, u.w, q0_.w)
      FDOT2(py, u.x, q1_.x) FDOT2(py, u.y, q1_.y)
      FDOT2(py, u.z, q1_.z) FDOT2(py, u.w, q1_.w)
      FDOT2(pz, u.x, q2_.x) FDOT2(pz, u.y, q2_.y)
      FDOT2(pz, u.z, q2_.z) FDOT2(pz, u.w, q2_.w)
      FDOT2(pw, u.x, q3_.x) FDOT2(pw, u.y, q3_.y)
      FDOT2(pw, u.z, q3_.z) FDOT2(pw, u.w, q3_.w)
      ax = fmaf(px, nn_, ax);
      ay = fmaf(py, nn_, ay);
      az = fmaf(pz, nn_, az);
      aw = fmaf(pw, nn_, aw);
      ++e;
    }
  }
  while (cur < hi) {
    float4 res = {ax, ay, az, aw};
    *(float4*)(agg + (long)cur * 256 + (l << 2)) = res;
    ax = ay = az = aw = 0.f;
    ++cur;
  }
#undef L2_FLUSH
}

// ================= MSG PATH: per-group relation-batched GEMM ==========
__global__ __launch_bounds__(256, 4) void msg_gemm1g(
    int g, const int4* __restrict__ rec2, const int* __restrict__ offB,
    const int* __restrict__ tileOffB, const ushort_t* __restrict__ h0h,
    const ushort_t* __restrict__ Wh, ushort_t* __restrict__ msg) {
  __shared__ __align__(16) ushort_t smem[4][2048];
  int tid_g = tileOffB[g * NREL] + blockIdx.x;
  if (tid_g >= tileOffB[(g + 1) * NREL]) return;
  int lo = g * NREL, hi = (g + 1) * NREL;
  while (lo + 1 < hi) {
    int mid = (lo + hi) >> 1;
    if (tileOffB[mid] <= tid_g) lo = mid;
    else hi = mid;
  }
  int b = lo;
  int rrel = b - g * NREL;
  int t = tid_g - tileOffB[b];
  int ebase = offB[b] + t * TILE_E;
  int m64 = offB[b + 1] - offB[b] - t * TILE_E;
  if (m64 > TILE_E) m64 = TILE_E;
  int wid = threadIdx.x >> 6, l = threadIdx.x & 63;
  int mw = m64 - wid * 16;
  mw = mw < 0 ? 0 : (mw > 16 ? 16 : mw);
  if (mw <= 0) return;
  const uint4* Wp = (const uint4*)(Wh + (size_t)rrel * 1024 + (size_t)l * 16);
  uint4 q0 = Wp[0], q1 = Wp[1];
  int4 r2 = make_int4(0, 0, 0, 0);
  if (l < mw) r2 = rec2[ebase + wid * 16 + l];
  STAGE16R(h0h, smem[wid], r2, mw, l)
  int hoff = (l >> 2) << 3;
  for (int k = 0; k < mw; ++k) {
    int p = __shfl(r2.y, k);
    float nn = __uint_as_float((uint_t)__shfl(r2.z, k));
    uint4 u = *(const uint4*)&smem[wid][(k << 7) + hoff];
    float p0 = 0.f, p1 = 0.f;
    FDOT2(p0, u.x, q0.x) FDOT2(p0, u.y, q0.y)
    FDOT2(p0, u.z, q0.z) FDOT2(p0, u.w, q0.w)
    FDOT2(p1, u.x, q1.x) FDOT2(p1, u.y, q1.y)
    FDOT2(p1, u.z, q1.z) FDOT2(p1, u.w, q1.w)
    p0 *= nn;
    p1 *= nn;
    uint_t ov = (uint_t)f2h(p0) | ((uint_t)f2h(p1) << 16);
    *(uint_t*)&msg[(long)p * 128 + (l << 1)] = ov;
  }
}

__global__ __launch_bounds__(256, 4) void msg_gemm2g(
    int g, const int4* __restrict__ rec2, const int* __restrict__ offB,
    const int* __restrict__ tileOffB, const ushort_t* __restrict__ h1h,
    const ushort_t* __restrict__ Wh, ushort_t* __restrict__ msg) {
  __shared__ __align__(16) ushort_t smem[4][2048];
  int tid_g = tileOffB[g * NREL] + blockIdx.x;
  if (tid_g >= tileOffB[(g + 1) * NREL]) return;
  int lo = g * NREL, hi = (g + 1) * NREL;
  while (lo + 1 < hi) {
    int mid = (lo + hi) >> 1;
    if (tileOffB[mid] <= tid_g) lo = mid;
    else hi = mid;
  }
  int b = lo;
  int rrel = b - g * NREL;
  int t = tid_g - tileOffB[b];
  int ebase = offB[b] + t * TILE_E;
  int m64 = offB[b + 1] - offB[b] - t * TILE_E;
  if (m64 > TILE_E) m64 = TILE_E;
  int wid = threadIdx.x >> 6, l = threadIdx.x & 63;
  int mw = m64 - wid * 16;
  mw = mw < 0 ? 0 : (mw > 16 ? 16 : mw);
  if (mw <= 0) return;
  const uint4* Wp = (const uint4*)(Wh + (size_t)rrel * 2048 + (size_t)l * 32);
  uint4 q0 = Wp[0], q1 = Wp[1], q2 = Wp[2], q3 = Wp[3];
  int4 r2 = make_int4(0, 0, 0, 0);
  if (l < mw) r2 = rec2[ebase + wid * 16 + l];
  STAGE16R(h1h, smem[wid], r2, mw, l)
  int hoff = (l >> 2) << 3;
  for (int k = 0; k < mw; ++k) {
    int p = __shfl(r2.y, k);
    float nn = __uint_as_float((uint_t)__shfl(r2.z, k));
    uint4 u = *(const uint4*)&smem[wid][(k << 7) + hoff];
    float px = 0.f, py = 0.f, pz = 0.f, pw = 0.f;
    FDOT2(px, u.x, q0.x) FDOT2(px, u.y, q0.y)
    FDOT2(px, u.z, q0.z) FDOT2(px, u.w, q0.w)
    FDOT2(py, u.x, q1.x) FDOT2(py, u.y, q1.y)
    FDOT2(py, u.z, q1.z) FDOT2(py, u.w, q1.w)
    FDOT2(pz, u.x, q2.x) FDOT2(pz, u.y, q2.y)
    FDOT2(pz, u.z, q2.z) FDOT2(pz, u.w, q2.w)
    FDOT2(pw, u.x, q3.x) FDOT2(pw, u.y, q3.y)
    FDOT2(pw, u.z, q3.z) FDOT2(pw, u.w, q3.w)
    px *= nn;
    py *= nn;
    pz *= nn;
    pw *= nn;
    uint2 ov;
    ov.x = (uint_t)f2h(px) | ((uint_t)f2h(py) << 16);
    ov.y = (uint_t)f2h(pz) | ((uint_t)f2h(pw) << 16);
    *(uint2*)&msg[(long)p * 256 + (l << 2)] = ov;
  }
}

// ========== Node layer 1 (fallback: agg input) ==========
__global__ __launch_bounds__(256) void node_layer1(
    const ushort_t* __restrict__ h0h, const float* __restrict__ loop1,
    const float* __restrict__ agg1, const float* __restrict__ bias,
    ushort_t* __restrict__ h1h) {
  __shared__ __align__(8) ushort_t Lh[128 * 130];
  __shared__ __align__(8) ushort_t hs[NT * 128];
  int tid = threadIdx.x;
  for (int t = 0; t < 64; ++t) {
    int flat = t * 256 + tid;
    int i = flat >> 7, o = flat & 127;
    Lh[o * 130 + i] = f2h(loop1[i * 128 + o]);
  }
  __syncthreads();
  int o = tid & 127;
  int g = tid >> 7;
  for (int grp = blockIdx.x; grp < N_NODES / NT; grp += gridDim.x) {
    int n0 = grp * NT;
    __syncthreads();
    for (int t = 0; t < 4; ++t) {
      int flat = t * 256 + tid;
      int j = flat >> 7, i = flat & 127;
      hs[j * 128 + i] = h0h[(long)(n0 + j) * 128 + i];
    }
    __syncthreads();
    float acc[4] = {0.f, 0.f, 0.f, 0.f};
    const ushort_t* Lo = &Lh[o * 130];
    const ushort_t* hb = &hs[(g * 4) * 128];
    for (int i = 0; i < 128; i += 4) {
      uint_t lv01 = *(const uint_t*)&Lo[i];
      uint_t lv23 = *(const uint_t*)&Lo[i + 2];
#pragma unroll
      for (int j = 0; j < 4; ++j) {
        uint2 hj = *(const uint2*)&hb[j * 128 + i];
        FDOT2(acc[j], hj.x, lv01)
        FDOT2(acc[j], hj.y, lv23)
      }
    }
    float bo = bias[o];
#pragma unroll
    for (int j = 0; j < 4; ++j) {
      int n = n0 + g * 4 + j;
      float v = acc[j] + bo + agg1[(long)n * 128 + o];
      h1h[(long)n * 128 + o] = f2h(fmaxf(v, 0.f));
    }
  }
}

// ========== Node layer 2 fused (fallback: agg input) ==========
__global__ __launch_bounds__(256) void node_layer2f(
    const ushort_t* __restrict__ h1h, const float* __restrict__ loop2,
    const float* __restrict__ agg2, const float* __restrict__ bias2,
    const float* __restrict__ eps, float* __restrict__ out) {
  __shared__ __align__(8) ushort_t Lh[256 * 130];
  __shared__ __align__(8) ushort_t hs[NT * 128];
  __shared__ float spbuf[NT * 128];
  int o = threadIdx.x;
  for (int t = 0; t < 128; ++t) {
    int flat = t * 256 + o;
    int i = flat >> 8, c = flat & 255;
    Lh[c * 130 + i] = f2h(loop2[i * 256 + c]);
  }
  __syncthreads();
  for (int grp = blockIdx.x; grp < N_NODES / NT; grp += gridDim.x) {
    int n0 = grp * NT;
    __syncthreads();
    for (int t = 0; t < 4; ++t) {
      int flat = t * 256 + o;
      int j = flat >> 7, i = flat & 127;
      hs[j * 128 + i] = h1h[(long)(n0 + j) * 128 + i];
    }
    __syncthreads();
    float acc[NT] = {0.f, 0.f, 0.f, 0.f, 0.f, 0.f, 0.f, 0.f};
    const ushort_t* Lo = &Lh[o * 130];
    for (int i = 0; i < 128; i += 4) {
      uint_t lv01 = *(const uint_t*)&Lo[i];
      uint_t lv23 = *(const uint_t*)&Lo[i + 2];
#pragma unroll
      for (int j = 0; j < NT; ++j) {
        uint2 hj = *(const uint2*)&hs[j * 128 + i];
        FDOT2(acc[j], hj.x, lv01)
        FDOT2(acc[j], hj.y, lv23)
      }
    }
    float bo = bias2[o];
    if (o >= 128) {
      int oc = o - 128;
#pragma unroll
      for (int j = 0; j < NT; ++j) {
        float hv = acc[j] + bo + agg2[(long)(n0 + j) * 256 + o];
        float sp = fmaxf(hv, 0.f) + log1pf(expf(-fabsf(hv)));
        spbuf[j * 128 + oc] = sqrtf(sp + 1e-8f);
      }
    }
    __syncthreads();
    if (o < 128) {
#pragma unroll
      for (int j = 0; j < NT; ++j) {
        float mval = acc[j] + bo + agg2[(long)(n0 + j) * 256 + o];
        long off2_ = (long)(n0 + j) * 128 + o;
        out[off2_] = mval + spbuf[j * 128 + o] * eps[off2_];
      }
    }
  }
}

// ========== Node layer 1 (msg path, per group, global loop1T) ==========
__global__ __launch_bounds__(256) void node_layer1mg(
    int g, const ushort_t* __restrict__ h0h, const ushort_t* __restrict__ l1t,
    const ushort_t* __restrict__ msg1, const int* __restrict__ offsets,
    const float* __restrict__ bias, ushort_t* __restrict__ h1h) {
  __shared__ __align__(8) ushort_t hs[NT * 128];
  int tid = threadIdx.x;
  int o = tid & 127;
  int gg = tid >> 7;
  int ebg = offsets[g * GSZ];
  const ushort_t* Lo = l1t + (size_t)o * 128;
  float bo = bias[o];
  for (int tile = blockIdx.x; tile < GSZ / NT; tile += gridDim.x) {
    int n0 = g * GSZ + tile * NT;
    __syncthreads();
    for (int t = 0; t < 4; ++t) {
      int flat = t * 256 + tid;
      int j = flat >> 7, i = flat & 127;
      hs[j * 128 + i] = h0h[(long)(n0 + j) * 128 + i];
    }
    __syncthreads();
    float acc[4] = {0.f, 0.f, 0.f, 0.f};
    const ushort_t* hb = &hs[(gg * 4) * 128];
    for (int i = 0; i < 128; i += 4) {
      uint_t lv01 = *(const uint_t*)&Lo[i];
      uint_t lv23 = *(const uint_t*)&Lo[i + 2];
#pragma unroll
      for (int j = 0; j < 4; ++j) {
        uint2 hj = *(const uint2*)&hb[j * 128 + i];
        FDOT2(acc[j], hj.x, lv01)
        FDOT2(acc[j], hj.y, lv23)
      }
    }
#pragma unroll
    for (int j = 0; j < 4; ++j) {
      int n = n0 + gg * 4 + j;
      int s = offsets[n] - ebg, eN = offsets[n + 1] - ebg;
      float ag = 0.f;
      for (int k = s; k < eN; ++k) ag += h2f(msg1[(long)k * 128 + o]);
      float v = acc[j] + bo + ag;
      h1h[(long)n * 128 + o] = f2h(fmaxf(v, 0.f));
    }
  }
}

// ========== Node layer 2 fused (msg path, per group, global loop2T) =======
__global__ __launch_bounds__(256) void node_layer2fmg(
    int g, const ushort_t* __restrict__ h1h, const ushort_t* __restrict__ l2t,
    const ushort_t* __restrict__ msg2, const int* __restrict__ offsets,
    const float* __restrict__ bias2, const float* __restrict__ eps,
    float* __restrict__ out) {
  __shared__ __align__(8) ushort_t hs[NT * 128];
  __shared__ float spbuf[NT * 128];
  int o = threadIdx.x;
  int ebg = offsets[g * GSZ];
  const ushort_t* Lo = l2t + (size_t)o * 128;
  float bo = bias2[o];
  for (int tile = blockIdx.x; tile < GSZ / NT; tile += gridDim.x) {
    int n0 = g * GSZ + tile * NT;
    __syncthreads();
    for (int t = 0; t < 4; ++t) {
      int flat = t * 256 + o;
      int j = flat >> 7, i = flat & 127;
      hs[j * 128 + i] = h1h[(long)(n0 + j) * 128 + i];
    }
    __syncthreads();
    float acc[NT] = {0.f, 0.f, 0.f, 0.f, 0.f, 0.f, 0.f, 0.f};
    for (int i = 0; i < 128; i += 4) {
      uint_t lv01 = *(const uint_t*)&Lo[i];
      uint_t lv23 = *(const uint_t*)&Lo[i + 2];
#pragma unroll
      for (int j = 0; j < NT; ++j) {
        uint2 hj = *(const uint2*)&hs[j * 128 + i];
        FDOT2(acc[j], hj.x, lv01)
        FDOT2(acc[j], hj.y, lv23)
      }
    }
#pragma unroll
    for (int j = 0; j < NT; ++j) {
      int n = n0 + j;
      int s = offsets[n] - ebg, eN = offsets[n + 1] - ebg;
      float ag = 0.f;
      for (int k = s; k < eN; ++k) ag += h2f(msg2[(long)k * 256 + o]);
      acc[j] += bo + ag;
    }
    if (o >= 128) {
      int oc = o - 128;
#pragma unroll
      for (int j = 0; j < NT; ++j) {
        float hv = acc[j];
        float sp = fmaxf(hv, 0.f) + log1pf(expf(-fabsf(hv)));
        spbuf[j * 128 + oc] = sqrtf(sp + 1e-8f);
      }
    }
    __syncthreads();
    if (o < 128) {
#pragma unroll
      for (int j = 0; j < NT; ++j) {
        long off2_ = (long)(n0 + j) * 128 + o;
        out[off2_] = acc[j] + spbuf[j * 128 + o] * eps[off2_];
      }
    }
  }
}

extern "C" void kernel_launch(void* const* d_in, const int* in_sizes, int n_in,
                              void* d_out, int out_size, void* d_ws, size_t ws_size,
                              hipStream_t stream) {
  const int* node_ids = (const int*)d_in[0];
  const int* src      = (const int*)d_in[1];
  const int* dst      = (const int*)d_in[2];
  const int* etype    = (const int*)d_in[3];
  const float* norm   = (const float*)d_in[4];
  const float* emb    = (const float*)d_in[5];
  const float* W1     = (const float*)d_in[6];
  const float* loop1  = (const float*)d_in[7];
  const float* b1     = (const float*)d_in[8];
  const float* W2     = (const float*)d_in[9];
  const float* loop2  = (const float*)d_in[10];
  const float* b2     = (const float*)d_in[11];
  const float* eps    = (const float*)d_in[12];
  float* out = (float*)d_out;

  char* ws = (char*)d_ws;
  size_t off = 0;
  int* deg      = (int*)(ws + off); off += (size_t)N_NODES * 4;
  int* cursor   = (int*)(ws + off); off += (size_t)N_NODES * 4;
  int* cntB     = (int*)(ws + off); off += (size_t)NBUCK * 4;
  int* curB     = (int*)(ws + off); off += (size_t)NBUCK * 4;
  int* offsets  = (int*)(ws + off); off += (size_t)(N_NODES + 1) * 4;
  int* offB     = (int*)(ws + off); off += (size_t)(NBUCK + 1) * 4;
  int* tcB      = (int*)(ws + off); off += (size_t)NBUCK * 4;
  int* tileOffB = (int*)(ws + off); off += (size_t)(NBUCK + 1) * 4;
  int* ranges   = (int*)(ws + off); off += (size_t)(NW_AGG + 1) * 4;
  off = (off + 15) & ~(size_t)15;
  int4* rec     = (int4*)(ws + off); off += (size_t)N_EDGES * 16;
  ushort_t* h0h = (ushort_t*)(ws + off); off += (size_t)N_NODES * HDIM * 2;
  ushort_t* h1h = (ushort_t*)(ws + off); off += (size_t)N_NODES * HDIM * 2;
  ushort_t* Wh1 = (ushort_t*)(ws + off); off += (size_t)NREL * NBLK * 64 * 2;
  ushort_t* Wh2 = (ushort_t*)(ws + off); off += (size_t)NREL * NBLK * 128 * 2;
  ushort_t* l1t = (ushort_t*)(ws + off); off += (size_t)128 * 128 * 2;
  ushort_t* l2t = (ushort_t*)(ws + off); off += (size_t)256 * 128 * 2;
  off = (off + 15) & ~(size_t)15;
  size_t tail = off;
  size_t need_c = tail + (size_t)MAXE_G * 256 * 2;   // msg buffer (90 MB)
  bool use_c = (ws_size >= need_c);

  // ---- common build ----
  hipMemsetAsync(deg, 0, ((size_t)2 * N_NODES + 2 * NBUCK) * 4, stream);
  hist_deg<<<(N_EDGES + 255) / 256, 256, 0, stream>>>(dst, deg);
  conv_w1<<<(NREL * NBLK * 64 + 255) / 256, 256, 0, stream>>>(W1, Wh1);
  conv_w2<<<(NREL * NBLK * 128 + 255) / 256, 256, 0, stream>>>(W2, Wh2);
  scanN<<<1, 1024, 0, stream>>>(deg, offsets, N_NODES);
  conv_h0<<<(N_NODES * HDIM + 255) / 256, 256, 0, stream>>>(node_ids, emb, h0h);

  if (use_c) {
    ushort_t* msg = (ushort_t*)(ws + tail);
    const int T_G = MAXE_G / TILE_E + NREL;  // per-group tile grid bound
    conv_l1t<<<(128 * 128 + 255) / 256, 256, 0, stream>>>(loop1, l1t);
    conv_l2t<<<(128 * 256 + 255) / 256, 256, 0, stream>>>(loop2, l2t);
    hist_grel<<<(N_EDGES + 255) / 256, 256, 0, stream>>>(dst, etype, cntB);
    scanN<<<1, 1024, 0, stream>>>(cntB, offB, NBUCK);
    calc_tc<<<(NBUCK + 255) / 256, 256, 0, stream>>>(cntB, tcB);
    scanN<<<1, 1024, 0, stream>>>(tcB, tileOffB, NBUCK);
    scatter2g<<<(N_EDGES + 255) / 256, 256, 0, stream>>>(
        src, dst, etype, norm, offsets, cursor, offB, curB, rec);
    for (int g = 0; g < NG; ++g) {
      msg_gemm1g<<<T_G, 256, 0, stream>>>(g, rec, offB, tileOffB, h0h, Wh1, msg);
      node_layer1mg<<<512, 256, 0, stream>>>(g, h0h, l1t, msg, offsets, b1, h1h);
    }
    for (int g = 0; g < NG; ++g) {
      msg_gemm2g<<<T_G, 256, 0, stream>>>(g, rec, offB, tileOffB, h1h, Wh2, msg);
      node_layer2fmg<<<512, 256, 0, stream>>>(g, h1h, l2t, msg, offsets, b2,
                                              eps, out);
    }
  } else {
    float* agg2 = (float*)(ws + tail);
    float* agg1 = out;  // dead before node_layer2f writes out
    calc_ranges<<<(NW_AGG + 256) / 256, 256, 0, stream>>>(offsets, ranges);
    scatter_rec<<<(N_EDGES + 255) / 256, 256, 0, stream>>>(src, dst, etype, norm,
                                                           offsets, cursor, rec);
    agg_layer1<<<NW_AGG / 4, 256, 0, stream>>>(rec, offsets, ranges, h0h, Wh1, agg1);
    node_layer1<<<1024, 256, 0, stream>>>(h0h, loop1, agg1, b1, h1h);
    agg_layer2<<<NW_AGG / 4, 256, 0, stream>>>(rec, offsets, ranges, h1h, Wh2, agg2);
    node_layer2f<<<512, 256, 0, stream>>>(h1h, loop2, agg2, b2, eps, out);
  }
}

// Round 21
// 1122.992 us; speedup vs baseline: 4.3629x; 4.2683x over previous
//
#include <hip/hip_runtime.h>
#include <math.h>

#define N_NODES 100000
#define N_EDGES 1600000
#define HDIM 128
#define NBLK 16
#define NREL 200
#define NW_AGG 8192  // balanced waves
#define NT 8         // node-tile for node kernels

typedef unsigned short ushort_t;
typedef unsigned int uint_t;
typedef _Float16 h2 __attribute__((ext_vector_type(2)));

__device__ __forceinline__ ushort_t f2h(float f) {
  _Float16 h = (_Float16)f;
  return __builtin_bit_cast(unsigned short, h);
}
__device__ __forceinline__ float h2f(ushort_t b) {
  return (float)__builtin_bit_cast(_Float16, b);
}

#if defined(__has_builtin) && __has_builtin(__builtin_amdgcn_fdot2)
#define FDOT2(accv, au, bu)                                                    \
  accv = __builtin_amdgcn_fdot2(__builtin_bit_cast(h2, au),                    \
                                __builtin_bit_cast(h2, bu), accv, false);
#else
#define FDOT2(accv, au, bu)                                                    \
  {                                                                            \
    h2 av_ = __builtin_bit_cast(h2, au);                                       \
    h2 bv_ = __builtin_bit_cast(h2, bu);                                       \
    accv = fmaf((float)av_[0], (float)bv_[0], accv);                           \
    accv = fmaf((float)av_[1], (float)bv_[1], accv);                           \
  }
#endif

#if defined(__has_builtin) && __has_builtin(__builtin_amdgcn_global_load_lds)
#define HAVE_GLL 1
#else
#define HAVE_GLL 0
#endif

// Stage 32 h-rows (8KB) into wave slab.
#if HAVE_GLL
#define STAGE_H32(HSRC, SMEMW)                                                 \
  {                                                                            \
    _Pragma("unroll") for (int i_ = 0; i_ < 8; ++i_) {                         \
      int ei_ = (i_ << 2) + (l >> 4);                                          \
      if (ei_ >= m) ei_ = m - 1;                                               \
      int ss_ = __shfl(r.x, ei_);                                              \
      const ushort_t* gsrc_ = HSRC + ((long)ss_ << 7) + ((l & 15) << 3);       \
      __builtin_amdgcn_global_load_lds(                                        \
          (const __attribute__((address_space(1))) unsigned int*)gsrc_,        \
          (__attribute__((address_space(3))) unsigned int*)&SMEMW[i_ << 9],    \
          16, 0, 0);                                                           \
    }                                                                          \
    asm volatile("s_waitcnt vmcnt(0)" ::: "memory");                           \
  }
#else
#define STAGE_H32(HSRC, SMEMW)                                                 \
  {                                                                            \
    _Pragma("unroll") for (int i_ = 0; i_ < 8; ++i_) {                         \
      int ei_ = (i_ << 2) + (l >> 4);                                          \
      if (ei_ >= m) ei_ = m - 1;                                               \
      int ss_ = __shfl(r.x, ei_);                                              \
      const ushort_t* gsrc_ = HSRC + ((long)ss_ << 7) + ((l & 15) << 3);       \
      uint4 t_ = *(const uint4*)gsrc_;                                         \
      *(uint4*)&SMEMW[(i_ << 9) + (l << 3)] = t_;                              \
    }                                                                          \
  }
#endif

// ================= CSR build =================
__global__ __launch_bounds__(256) void hist_deg(const int* __restrict__ dst,
                                                int* __restrict__ deg) {
  int e = blockIdx.x * 256 + threadIdx.x;
  if (e < N_EDGES) atomicAdd(&deg[dst[e]], 1);
}

// exclusive scan; writes out[n] = total
__global__ __launch_bounds__(1024) void scanN(const int* __restrict__ in,
                                              int* __restrict__ out, int n) {
  __shared__ int wsum[16];
  __shared__ int carry_s;
  int tid = threadIdx.x, lane = tid & 63, wid = tid >> 6;
  if (tid == 0) carry_s = 0;
  __syncthreads();
  for (int base = 0; base < n; base += 1024) {
    int i = base + tid;
    int v = (i < n) ? in[i] : 0;
    int x = v;
#pragma unroll
    for (int s = 1; s < 64; s <<= 1) {
      int t = __shfl_up(x, s);
      if (lane >= s) x += t;
    }
    if (lane == 63) wsum[wid] = x;
    __syncthreads();
    if (wid == 0) {
      int y = (lane < 16) ? wsum[lane] : 0;
#pragma unroll
      for (int s = 1; s < 16; s <<= 1) {
        int t = __shfl_up(y, s);
        if (lane >= s) y += t;
      }
      if (lane < 16) wsum[lane] = y;
    }
    __syncthreads();
    int carry = carry_s;
    int wbase = (wid > 0) ? wsum[wid - 1] : 0;
    if (i < n) out[i] = carry + wbase + (x - v);
    __syncthreads();
    if (tid == 0) carry_s = carry + wsum[15];
    __syncthreads();
  }
  if (threadIdx.x == 0) out[n] = carry_s;
}

// dst-CSR 8-byte records: {src, etype<<16 | f16(norm)}
__global__ __launch_bounds__(256) void scatter_rec(
    const int* __restrict__ src, const int* __restrict__ dst,
    const int* __restrict__ etype, const float* __restrict__ norm,
    const int* __restrict__ offsets, int* __restrict__ cursor,
    int2* __restrict__ rec) {
  int e = blockIdx.x * 256 + threadIdx.x;
  if (e >= N_EDGES) return;
  int d = dst[e];
  int pos = offsets[d] + atomicAdd(&cursor[d], 1);
  int meta = (etype[e] << 16) | (int)(uint_t)f2h(norm[e]);
  rec[pos] = make_int2(src[e], meta);
}

// wave w owns nodes [ranges[w], ranges[w+1])
__global__ __launch_bounds__(256) void calc_ranges(const int* __restrict__ offsets,
                                                   int* __restrict__ ranges) {
  int w = blockIdx.x * 256 + threadIdx.x;
  if (w > NW_AGG) return;
  if (w == NW_AGG) {
    ranges[w] = N_NODES;
    return;
  }
  long t = ((long)w * N_EDGES + NW_AGG - 1) / NW_AGG;
  int lo = 0, hi = N_NODES;
  while (lo < hi) {
    int mid = (lo + hi) >> 1;
    if ((long)offsets[mid] >= t) hi = mid;
    else lo = mid + 1;
  }
  ranges[w] = lo;
}

__global__ __launch_bounds__(256) void conv_h0(const int* __restrict__ node_ids,
                                               const float* __restrict__ emb,
                                               ushort_t* __restrict__ h0h) {
  long gid = (long)blockIdx.x * 256 + threadIdx.x;
  if (gid >= (long)N_NODES * HDIM) return;
  int n = (int)(gid >> 7);
  int o = (int)(gid & 127);
  h0h[gid] = f2h(emb[(long)node_ids[n] * HDIM + o]);
}

// W1 (R,NB,8,8) fp32 -> f16 [rb][g(4)][c(2)][ip(4)][hi(2)] (i=ip*2+hi, o=g*2+c)
__global__ __launch_bounds__(256) void conv_w1(const float* __restrict__ W,
                                               ushort_t* __restrict__ Wh) {
  int idx = blockIdx.x * 256 + threadIdx.x;
  if (idx >= NREL * NBLK * 64) return;
  int rb = idx >> 6, i = (idx >> 3) & 7, o = idx & 7;
  int g = o >> 1, c = o & 1, ip = i >> 1, hi = i & 1;
  Wh[(((rb * 4 + g) * 2 + c) * 4 + ip) * 2 + hi] = f2h(W[idx]);
}

// W2 (R,NB,8,16) fp32 -> f16 [rb][g(4)][c(4)][ip(4)][hi(2)] (i=ip*2+hi, o=g*4+c)
__global__ __launch_bounds__(256) void conv_w2(const float* __restrict__ W,
                                               ushort_t* __restrict__ Wh) {
  int idx = blockIdx.x * 256 + threadIdx.x;
  if (idx >= NREL * NBLK * 128) return;
  int rb = idx >> 7, i = (idx >> 4) & 7, o = idx & 15;
  int g = o >> 2, c = o & 3, ip = i >> 1, hi = i & 1;
  Wh[(((rb * 4 + g) * 4 + c) * 4 + ip) * 2 + hi] = f2h(W[idx]);
}

// ================= Layer-1 aggregation (LDS-staged h, chunk 32) ===========
__global__ __launch_bounds__(256, 4) void agg_layer1(
    const int2* __restrict__ rec, const int* __restrict__ offsets,
    const int* __restrict__ ranges, const ushort_t* __restrict__ h0h,
    const ushort_t* __restrict__ Wh, float* __restrict__ agg) {
  __shared__ __align__(16) ushort_t smem[4][4096];
  int w = blockIdx.x * 4 + (threadIdx.x >> 6);
  int l = threadIdx.x & 63;
  int wid = threadIdx.x >> 6;
  int lo = ranges[w], hi = ranges[w + 1];
  if (lo >= hi) return;
  const ushort_t* Wl = Wh + (size_t)l * 16;
  int hoff = (l >> 2) << 3;
  int estart = offsets[lo];
  int ecnt = offsets[hi] - estart;
  int cur = lo;
  int next_b = offsets[lo + 1];
  int e = estart;
  float ac0 = 0.f, ac1 = 0.f;
#define L1_FLUSH                                                               \
  {                                                                            \
    float2 res = {ac0, ac1};                                                   \
    *(float2*)(agg + (long)cur * HDIM + (l << 1)) = res;                       \
    ac0 = ac1 = 0.f;                                                           \
    ++cur;                                                                     \
    next_b = offsets[cur + 1];                                                 \
  }
  for (int c0 = 0; c0 < ecnt; c0 += 32) {
    int m = min(32, ecnt - c0);
    int2 r = make_int2(0, 0);
    if (l < m) r = rec[estart + c0 + l];
    STAGE_H32(h0h, smem[wid])
    for (int k = 0; k < m; ++k) {
      while (e == next_b) L1_FLUSH
      uint_t meta = (uint_t)__shfl(r.y, k);
      int wy_ = meta >> 16;
      float nn_ = h2f((ushort_t)(meta & 0xFFFFu));
      const uint4* Wp_ = (const uint4*)(Wl + (size_t)wy_ * 1024);
      uint4 q0_ = Wp_[0], q1_ = Wp_[1];
      uint4 u = *(const uint4*)&smem[wid][(k << 7) + hoff];
      float p0 = 0.f, p1 = 0.f;
      FDOT2(p0, u.x, q0_.x) FDOT2(p0, u.y, q0_.y)
      FDOT2(p0, u.z, q0_.z) FDOT2(p0, u.w, q0_.w)
      FDOT2(p1, u.x, q1_.x) FDOT2(p1, u.y, q1_.y)
      FDOT2(p1, u.z, q1_.z) FDOT2(p1, u.w, q1_.w)
      ac0 = fmaf(p0, nn_, ac0);
      ac1 = fmaf(p1, nn_, ac1);
      ++e;
    }
  }
  while (cur < hi) {
    float2 res = {ac0, ac1};
    *(float2*)(agg + (long)cur * HDIM + (l << 1)) = res;
    ac0 = ac1 = 0.f;
    ++cur;
  }
#undef L1_FLUSH
}

// ================= Layer-2 aggregation (LDS-staged h, chunk 32) ===========
__global__ __launch_bounds__(256, 4) void agg_layer2(
    const int2* __restrict__ rec, const int* __restrict__ offsets,
    const int* __restrict__ ranges, const ushort_t* __restrict__ h1h,
    const ushort_t* __restrict__ Wh, float* __restrict__ agg) {
  __shared__ __align__(16) ushort_t smem[4][4096];
  int w = blockIdx.x * 4 + (threadIdx.x >> 6);
  int l = threadIdx.x & 63;
  int wid = threadIdx.x >> 6;
  int lo = ranges[w], hi = ranges[w + 1];
  if (lo >= hi) return;
  const ushort_t* Wl = Wh + (size_t)l * 32;
  int hoff = (l >> 2) << 3;
  int estart = offsets[lo];
  int ecnt = offsets[hi] - estart;
  int cur = lo;
  int next_b = offsets[lo + 1];
  int e = estart;
  float ax = 0.f, ay = 0.f, az = 0.f, aw = 0.f;
#define L2_FLUSH                                                               \
  {                                                                            \
    float4 res = {ax, ay, az, aw};                                             \
    *(float4*)(agg + (long)cur * 256 + (l << 2)) = res;                        \
    ax = ay = az = aw = 0.f;                                                   \
    ++cur;                                                                     \
    next_b = offsets[cur + 1];                                                 \
  }
  for (int c0 = 0; c0 < ecnt; c0 += 32) {
    int m = min(32, ecnt - c0);
    int2 r = make_int2(0, 0);
    if (l < m) r = rec[estart + c0 + l];
    STAGE_H32(h1h, smem[wid])
    for (int k = 0; k < m; ++k) {
      while (e == next_b) L2_FLUSH
      uint_t meta = (uint_t)__shfl(r.y, k);
      int wy_ = meta >> 16;
      float nn_ = h2f((ushort_t)(meta & 0xFFFFu));
      const uint4* Wp_ = (const uint4*)(Wl + (size_t)wy_ * 2048);
      uint4 q0_ = Wp_[0], q1_ = Wp_[1], q2_ = Wp_[2], q3_ = Wp_[3];
      uint4 u = *(const uint4*)&smem[wid][(k << 7) + hoff];
      float px = 0.f, py = 0.f, pz = 0.f, pw = 0.f;
      FDOT2(px, u.x, q0_.x) FDOT2(px, u.y, q0_.y)
      FDOT2(px, u.z, q0_.z) FDOT2(px, u.w, q0_.w)
      FDOT2(py, u.x, q1_.x) FDOT2(py, u.y, q1_.y)
      FDOT2(py, u.z, q1_.z) FDOT2(py, u.w, q1_.w)
      FDOT2(pz, u.x, q2_.x) FDOT2(pz, u.y, q2_.y)
      FDOT2(pz, u.z, q2_.z) FDOT2(pz, u.w, q2_.w)
      FDOT2(pw, u.x, q3_.x) FDOT2(pw, u.y, q3_.y)
      FDOT2(pw, u.z, q3_.z) FDOT2(pw, u.w, q3_.w)
      ax = fmaf(px, nn_, ax);
      ay = fmaf(py, nn_, ay);
      az = fmaf(pz, nn_, az);
      aw = fmaf(pw, nn_, aw);
      ++e;
    }
  }
  while (cur < hi) {
    float4 res = {ax, ay, az, aw};
    *(float4*)(agg + (long)cur * 256 + (l << 2)) = res;
    ax = ay = az = aw = 0.f;
    ++cur;
  }
#undef L2_FLUSH
}

// ========== Node layer 1: register-tiled, f16 L in LDS ==========
__global__ __launch_bounds__(256) void node_layer1(
    const ushort_t* __restrict__ h0h, const float* __restrict__ loop1,
    const float* __restrict__ agg1, const float* __restrict__ bias,
    ushort_t* __restrict__ h1h) {
  __shared__ __align__(8) ushort_t Lh[128 * 130];
  __shared__ __align__(8) ushort_t hs[NT * 128];
  int tid = threadIdx.x;
  for (int t = 0; t < 64; ++t) {
    int flat = t * 256 + tid;
    int i = flat >> 7, o = flat & 127;
    Lh[o * 130 + i] = f2h(loop1[i * 128 + o]);
  }
  __syncthreads();
  int o = tid & 127;
  int g = tid >> 7;
  for (int grp = blockIdx.x; grp < N_NODES / NT; grp += gridDim.x) {
    int n0 = grp * NT;
    __syncthreads();
    for (int t = 0; t < 4; ++t) {
      int flat = t * 256 + tid;
      int j = flat >> 7, i = flat & 127;
      hs[j * 128 + i] = h0h[(long)(n0 + j) * 128 + i];
    }
    __syncthreads();
    float acc[4] = {0.f, 0.f, 0.f, 0.f};
    const ushort_t* Lo = &Lh[o * 130];
    const ushort_t* hb = &hs[(g * 4) * 128];
    for (int i = 0; i < 128; i += 4) {
      uint_t lv01 = *(const uint_t*)&Lo[i];
      uint_t lv23 = *(const uint_t*)&Lo[i + 2];
#pragma unroll
      for (int j = 0; j < 4; ++j) {
        uint2 hj = *(const uint2*)&hb[j * 128 + i];
        FDOT2(acc[j], hj.x, lv01)
        FDOT2(acc[j], hj.y, lv23)
      }
    }
    float bo = bias[o];
#pragma unroll
    for (int j = 0; j < 4; ++j) {
      int n = n0 + g * 4 + j;
      float v = acc[j] + bo + agg1[(long)n * 128 + o];
      h1h[(long)n * 128 + o] = f2h(fmaxf(v, 0.f));
    }
  }
}

// ========== Node layer 2 fused: m + hv + gaussian sample ==========
__global__ __launch_bounds__(256) void node_layer2f(
    const ushort_t* __restrict__ h1h, const float* __restrict__ loop2,
    const float* __restrict__ agg2, const float* __restrict__ bias2,
    const float* __restrict__ eps, float* __restrict__ out) {
  __shared__ __align__(8) ushort_t Lh[256 * 130];
  __shared__ __align__(8) ushort_t hs[NT * 128];
  __shared__ float spbuf[NT * 128];
  int o = threadIdx.x;
  for (int t = 0; t < 128; ++t) {
    int flat = t * 256 + o;
    int i = flat >> 8, c = flat & 255;
    Lh[c * 130 + i] = f2h(loop2[i * 256 + c]);
  }
  __syncthreads();
  for (int grp = blockIdx.x; grp < N_NODES / NT; grp += gridDim.x) {
    int n0 = grp * NT;
    __syncthreads();
    for (int t = 0; t < 4; ++t) {
      int flat = t * 256 + o;
      int j = flat >> 7, i = flat & 127;
      hs[j * 128 + i] = h1h[(long)(n0 + j) * 128 + i];
    }
    __syncthreads();
    float acc[NT] = {0.f, 0.f, 0.f, 0.f, 0.f, 0.f, 0.f, 0.f};
    const ushort_t* Lo = &Lh[o * 130];
    for (int i = 0; i < 128; i += 4) {
      uint_t lv01 = *(const uint_t*)&Lo[i];
      uint_t lv23 = *(const uint_t*)&Lo[i + 2];
#pragma unroll
      for (int j = 0; j < NT; ++j) {
        uint2 hj = *(const uint2*)&hs[j * 128 + i];
        FDOT2(acc[j], hj.x, lv01)
        FDOT2(acc[j], hj.y, lv23)
      }
    }
    float bo = bias2[o];
    if (o >= 128) {
      int oc = o - 128;
#pragma unroll
      for (int j = 0; j < NT; ++j) {
        float hv = acc[j] + bo + agg2[(long)(n0 + j) * 256 + o];
        float sp = fmaxf(hv, 0.f) + log1pf(expf(-fabsf(hv)));
        spbuf[j * 128 + oc] = sqrtf(sp + 1e-8f);
      }
    }
    __syncthreads();
    if (o < 128) {
#pragma unroll
      for (int j = 0; j < NT; ++j) {
        float mval = acc[j] + bo + agg2[(long)(n0 + j) * 256 + o];
        long off2_ = (long)(n0 + j) * 128 + o;
        out[off2_] = mval + spbuf[j * 128 + o] * eps[off2_];
      }
    }
  }
}

extern "C" void kernel_launch(void* const* d_in, const int* in_sizes, int n_in,
                              void* d_out, int out_size, void* d_ws, size_t ws_size,
                              hipStream_t stream) {
  const int* node_ids = (const int*)d_in[0];
  const int* src      = (const int*)d_in[1];
  const int* dst      = (const int*)d_in[2];
  const int* etype    = (const int*)d_in[3];
  const float* norm   = (const float*)d_in[4];
  const float* emb    = (const float*)d_in[5];
  const float* W1     = (const float*)d_in[6];
  const float* loop1  = (const float*)d_in[7];
  const float* b1     = (const float*)d_in[8];
  const float* W2     = (const float*)d_in[9];
  const float* loop2  = (const float*)d_in[10];
  const float* b2     = (const float*)d_in[11];
  const float* eps    = (const float*)d_in[12];
  float* out = (float*)d_out;

  char* ws = (char*)d_ws;
  size_t off = 0;
  int* deg      = (int*)(ws + off); off += (size_t)N_NODES * 4;
  int* cursor   = (int*)(ws + off); off += (size_t)N_NODES * 4;
  int* offsets  = (int*)(ws + off); off += (size_t)(N_NODES + 1) * 4;
  int* ranges   = (int*)(ws + off); off += (size_t)(NW_AGG + 1) * 4;
  off = (off + 15) & ~(size_t)15;
  int2* rec     = (int2*)(ws + off); off += (size_t)N_EDGES * 8;
  ushort_t* h0h = (ushort_t*)(ws + off); off += (size_t)N_NODES * HDIM * 2;
  ushort_t* h1h = (ushort_t*)(ws + off); off += (size_t)N_NODES * HDIM * 2;
  ushort_t* Wh1 = (ushort_t*)(ws + off); off += (size_t)NREL * NBLK * 64 * 2;
  ushort_t* Wh2 = (ushort_t*)(ws + off); off += (size_t)NREL * NBLK * 128 * 2;
  off = (off + 15) & ~(size_t)15;
  float* agg2 = (float*)(ws + off);
  float* agg1 = out;  // agg1 lives in d_out (dead before node_layer2f writes)

  // ---- CSR build + f16 conversions ----
  hipMemsetAsync(deg, 0, (size_t)2 * N_NODES * 4, stream);  // deg + cursor
  hist_deg<<<(N_EDGES + 255) / 256, 256, 0, stream>>>(dst, deg);
  conv_w1<<<(NREL * NBLK * 64 + 255) / 256, 256, 0, stream>>>(W1, Wh1);
  conv_w2<<<(NREL * NBLK * 128 + 255) / 256, 256, 0, stream>>>(W2, Wh2);
  scanN<<<1, 1024, 0, stream>>>(deg, offsets, N_NODES);
  calc_ranges<<<(NW_AGG + 256) / 256, 256, 0, stream>>>(offsets, ranges);
  scatter_rec<<<(N_EDGES + 255) / 256, 256, 0, stream>>>(src, dst, etype, norm,
                                                         offsets, cursor, rec);
  conv_h0<<<(N_NODES * HDIM + 255) / 256, 256, 0, stream>>>(node_ids, emb, h0h);

  // ---- layer 1 ----
  agg_layer1<<<NW_AGG / 4, 256, 0, stream>>>(rec, offsets, ranges, h0h, Wh1, agg1);
  node_layer1<<<1024, 256, 0, stream>>>(h0h, loop1, agg1, b1, h1h);

  // ---- layer 2 ----
  agg_layer2<<<NW_AGG / 4, 256, 0, stream>>>(rec, offsets, ranges, h1h, Wh2, agg2);
  node_layer2f<<<512, 256, 0, stream>>>(h1h, loop2, agg2, b2, eps, out);
}